// Round 7
// baseline (388.721 us; speedup 1.0000x reference)
//
#include <hip/hip_runtime.h>

#define D_MODEL 1024
#define SEQ_L   2048
#define NHEADS  16
#define HDIM    64
#define NROWS   4096   // B*L

// Q is pre-scaled by (1/sqrt(64)) * log2(e) so softmax uses exp2 directly.
#define QSCALE 0.18033688011112042f
#define LOG2E  1.4426950408889634f

#if __has_builtin(__builtin_amdgcn_exp2f)
#define EXP2F(x) __builtin_amdgcn_exp2f(x)
#else
#define EXP2F(x) __expf((x) * 0.6931471805599453f)
#endif

typedef __attribute__((ext_vector_type(8))) short short8;
typedef __attribute__((ext_vector_type(4))) short short4v;
typedef __attribute__((ext_vector_type(4))) float floatx4;
typedef __attribute__((ext_vector_type(4))) unsigned short ushort4v;
typedef unsigned short ushort;

static __device__ __forceinline__ ushort f2bf(float f) {
    unsigned int u = __float_as_uint(f);
    u += 0x7FFFu + ((u >> 16) & 1u);
    return (ushort)(u >> 16);
}

static __device__ __forceinline__ floatx4 mfma16(short8 a, short8 b, floatx4 c) {
    return __builtin_amdgcn_mfma_f32_16x16x32_bf16(a, b, c, 0, 0, 0);
}

static __device__ __forceinline__ floatx4 mfma16k16(short4v a, short4v b, floatx4 c) {
    return __builtin_amdgcn_mfma_f32_16x16x16bf16_1k(a, b, c, 0, 0, 0);
}

static __device__ __forceinline__ void store8bf(ushort* dst, float4 a, float4 b) {
    uint4 pk;
    pk.x = (unsigned)f2bf(a.x) | ((unsigned)f2bf(a.y) << 16);
    pk.y = (unsigned)f2bf(a.z) | ((unsigned)f2bf(a.w) << 16);
    pk.z = (unsigned)f2bf(b.x) | ((unsigned)f2bf(b.y) << 16);
    pk.w = (unsigned)f2bf(b.z) | ((unsigned)f2bf(b.w) << 16);
    *(uint4*)dst = pk;
}

// async global->LDS, 16B per lane. LDS dest must be wave-uniform base + lane*16
// (we swizzle the GLOBAL source per lane; the LDS side stays lane-linear).
static __device__ __forceinline__ void gll16(const ushort* g, ushort* l) {
    __builtin_amdgcn_global_load_lds(
        (const __attribute__((address_space(1))) unsigned int*)(const unsigned int*)g,
        (__attribute__((address_space(3))) unsigned int*)(unsigned int*)l,
        16, 0, 0);
}

// ---------------------------------------------------------------------------
// Kernel 0: fp32 -> bf16 conversion of x and weights.
// ---------------------------------------------------------------------------
__global__ __launch_bounds__(256) void convert_bf16(
    const float* __restrict__ x,
    const float* __restrict__ wq, const float* __restrict__ wk,
    const float* __restrict__ wv, const float* __restrict__ wo,
    ushort* __restrict__ xb, ushort* __restrict__ wb3, ushort* __restrict__ wob)
{
    const int seg = blockIdx.y;
    const float* src;
    ushort* dst;
    int n;
    if      (seg == 0) { src = x;  dst = xb;                n = 4194304; }
    else if (seg == 1) { src = wq; dst = wb3;               n = 1048576; }
    else if (seg == 2) { src = wk; dst = wb3 + 1048576;     n = 1048576; }
    else if (seg == 3) { src = wv; dst = wb3 + 2097152;     n = 1048576; }
    else               { src = wo; dst = wob;               n = 1048576; }
    const int i = (blockIdx.x * 256 + threadIdx.x) * 8;
    if (i >= n) return;
    float4 a = *(const float4*)(src + i);
    float4 b = *(const float4*)(src + i + 4);
    store8bf(dst + i, a, b);
}

// ---------------------------------------------------------------------------
// Kernel 1: fused QKV GEMM. 64(M)x128(N) tiles, grid 24x64 = 1536 blocks =
// 6 blocks/CU (one full generation) — occupancy-first, single-buffered.
// Q/K use SWAPPED operand order (C^T) -> ushort4 epilogue stores.
// ---------------------------------------------------------------------------
__global__ __launch_bounds__(256, 6) void gemm_qkv(
    const ushort* __restrict__ A, const ushort* __restrict__ B,
    const float* __restrict__ bq, const float* __restrict__ bk,
    const float* __restrict__ bv,
    ushort* __restrict__ Qo, ushort* __restrict__ Ko, ushort* __restrict__ Vo)
{
    __shared__ ushort As[64 * 32];
    __shared__ ushort Bs[128 * 32];

    const int tid  = threadIdx.x;
    const int w    = tid >> 6;
    const int lane = tid & 63;
    const int l15  = lane & 15;
    const int quad = lane >> 4;

    const int bm = blockIdx.y * 64;     // x-row tile
    const int bn = blockIdx.x * 128;    // weight-col tile (0..3071)
    const int z  = blockIdx.x >> 3;     // 0=Q, 1=K, 2=V

    const int r0 = w * 16 + (lane >> 2);   // A row / B row round 0 (0..63)
    const int r1 = r0 + 64;                // B row round 1
    const int c_ = lane & 3;
    const int g0 = c_ ^ ((r0 >> 1) & 3);   // swizzled GLOBAL chunk
    const int g1 = c_ ^ ((r1 >> 1) & 3);

    const ushort* a0p = A + (size_t)(bm + r0) * 1024 + g0 * 8;
    const ushort* b0p = B + (size_t)(bn + r0) * 1024 + g0 * 8;
    const ushort* b1p = B + (size_t)(bn + r1) * 1024 + g1 * 8;
    ushort* lA0 = &As[r0 * 32 + c_ * 8];
    ushort* lB0 = &Bs[r0 * 32 + c_ * 8];
    ushort* lB1 = &Bs[r1 * 32 + c_ * 8];

    const int cA = (quad ^ ((l15 >> 1) & 3)) * 8;   // swizzled read chunk

    floatx4 acc[4][2];
#pragma unroll
    for (int i = 0; i < 4; i++)
#pragma unroll
        for (int j = 0; j < 2; j++) acc[i][j] = (floatx4){0.f, 0.f, 0.f, 0.f};

    for (int k0 = 0; k0 < 1024; k0 += 32) {
        __syncthreads();
        gll16(a0p + k0, lA0);
        gll16(b0p + k0, lB0);
        gll16(b1p + k0, lB1);
        __syncthreads();

        short8 af[4], bf[2];
#pragma unroll
        for (int mi = 0; mi < 4; mi++)
            af[mi] = *(const short8*)&As[(mi * 16 + l15) * 32 + cA];
#pragma unroll
        for (int ni = 0; ni < 2; ni++)
            bf[ni] = *(const short8*)&Bs[(w * 32 + ni * 16 + l15) * 32 + cA];
        if (z == 2) {
#pragma unroll
            for (int mi = 0; mi < 4; mi++)
#pragma unroll
                for (int ni = 0; ni < 2; ni++)
                    acc[mi][ni] = mfma16(af[mi], bf[ni], acc[mi][ni]);
        } else {
#pragma unroll
            for (int mi = 0; mi < 4; mi++)
#pragma unroll
                for (int ni = 0; ni < 2; ni++)
                    acc[mi][ni] = mfma16(bf[ni], af[mi], acc[mi][ni]);
        }
    }

    const int cwbase = bn & 1023;     // weight-col base within this matrix
    if (z == 2) {
        // ----- V epilogue (normal): lane col = l15, rows quad*4+r -> V^T store
#pragma unroll
        for (int ni = 0; ni < 2; ni++) {
            const int within = cwbase + w * 32 + ni * 16 + l15;
            const int h  = within >> 6;
            const int hd = within & 63;
            const float bvl = bv[within];
#pragma unroll
            for (int mi = 0; mi < 4; mi++) {
                const int row = bm + mi * 16 + quad * 4;
                const int bb = row >> 11, li = row & 2047;
                ushort4v pk;
#pragma unroll
                for (int r = 0; r < 4; r++) pk[r] = f2bf(acc[mi][ni][r] + bvl);
                *(ushort4v*)(Vo + ((size_t)(bb * NHEADS + h) * HDIM + hd) * SEQ_L + li) = pk;
            }
        }
    } else {
        // ----- Q/K epilogue (C^T): lane holds 4 consecutive weight cols -----
        const float* bias = z ? bk : bq;
        const float scale = z ? 1.0f : QSCALE;
        ushort* outp = z ? Ko : Qo;
#pragma unroll
        for (int ni = 0; ni < 2; ni++) {
            const int colw = cwbase + w * 32 + ni * 16 + quad * 4;
            const int h   = colw >> 6;
            const int hd0 = colw & 63;
            const float4 bb4 = *(const float4*)&bias[colw];
#pragma unroll
            for (int mi = 0; mi < 4; mi++) {
                const int row = bm + mi * 16 + l15;
                const int bb = row >> 11, li = row & 2047;
                ushort4v pk;
                pk[0] = f2bf((acc[mi][ni][0] + bb4.x) * scale);
                pk[1] = f2bf((acc[mi][ni][1] + bb4.y) * scale);
                pk[2] = f2bf((acc[mi][ni][2] + bb4.z) * scale);
                pk[3] = f2bf((acc[mi][ni][3] + bb4.w) * scale);
                *(ushort4v*)(outp + ((size_t)(bb * NHEADS + h) * SEQ_L + li) * HDIM + hd0) = pk;
            }
        }
    }
}

// ---------------------------------------------------------------------------
// Kernel 2: flash attention, S^T formulation, 128-query blocks, 2-way K-split.
// ---------------------------------------------------------------------------
__global__ __launch_bounds__(256, 4) void attn(
    const ushort* __restrict__ Q,
    const ushort* __restrict__ K,
    const ushort* __restrict__ Vt,
    const float* __restrict__ lam,
    ushort* __restrict__ O0, ushort* __restrict__ O1,
    float* __restrict__ Lw)
{
    __shared__ float mtab[128];
    __shared__ ushort Ks[2][64 * 64];
    __shared__ ushort Vts[2][64 * 64];

    const int tid  = threadIdx.x;
    const int wave = tid >> 6;
    const int lane = tid & 63;
    const int l15  = lane & 15;
    const int quad = lane >> 4;

    const int qb = blockIdx.x;           // 0..15
    const int h  = blockIdx.y;
    const int zz = blockIdx.z;           // 0..3
    const int bz = zz >> 1;
    const int sp = zz & 1;               // key split
    const int bh = bz * NHEADS + h;
    const int q0 = qb * 128;
    const int kb = sp * 1024;            // key base

    const float lambda = *lam;
    if (tid < 128) {
        float d  = (float)tid;
        float e1 = (d - 1.f) * (d - 1.f);
        float e2 = (d - 30.f) * (d - 30.f);
        mtab[tid] = LOG2E * lambda *
                    (0.8f * __expf(-2.0f * e1) + 0.4f * __expf(-0.125f * e2));
    }

    const ushort* qp =
        Q + ((size_t)bh * SEQ_L + q0 + wave * 16 + l15) * HDIM + quad * 8;
    short8 qf[2][2];
    qf[0][0] = *(const short8*)qp;
    qf[0][1] = *(const short8*)(qp + 32);
    qf[1][0] = *(const short8*)(qp + 64 * HDIM);
    qf[1][1] = *(const short8*)(qp + 64 * HDIM + 32);

    const ushort* kbase = K  + ((size_t)bh * SEQ_L) * HDIM;
    const ushort* vbase = Vt + ((size_t)bh * HDIM) * SEQ_L;

    const int cid0 = tid, cid1 = 256 + tid;
    const int row0 = cid0 >> 3, row1 = cid1 >> 3;
    const int cl0  = (cid0 & 7) ^ (row0 & 7);
    const int cl1  = (cid1 & 7) ^ (row1 & 7);
    const ushort* kg0 = kbase + (size_t)(kb + row0) * HDIM + cl0 * 8;
    const ushort* kg1 = kbase + (size_t)(kb + row1) * HDIM + cl1 * 8;
    const ushort* vg0 = vbase + (size_t)row0 * SEQ_L + kb + cl0 * 8;
    const ushort* vg1 = vbase + (size_t)row1 * SEQ_L + kb + cl1 * 8;

    floatx4 o[2][4];
#pragma unroll
    for (int g = 0; g < 2; g++)
#pragma unroll
        for (int i = 0; i < 4; i++) o[g][i] = (floatx4){0.f, 0.f, 0.f, 0.f};
    floatx4 ol[2];
    ol[0] = (floatx4){0.f, 0.f, 0.f, 0.f};
    ol[1] = (floatx4){0.f, 0.f, 0.f, 0.f};

    short4v ones;
    ones[0] = 0x3F80; ones[1] = 0x3F80; ones[2] = 0x3F80; ones[3] = 0x3F80;

    gll16(kg0, &Ks[0][cid0 * 8]);
    gll16(kg1, &Ks[0][cid1 * 8]);
    gll16(vg0, &Vts[0][cid0 * 8]);
    gll16(vg1, &Vts[0][cid1 * 8]);

    const int xo = l15 & 7;

    for (int t = 0; t < 16; t++) {
        const int cur = t & 1;
        __syncthreads();
        if (t + 1 < 16) {
            const int nxt = cur ^ 1;
            const int koff = (t + 1) * 64;
            gll16(kg0 + (size_t)koff * HDIM, &Ks[nxt][cid0 * 8]);
            gll16(kg1 + (size_t)koff * HDIM, &Ks[nxt][cid1 * 8]);
            gll16(vg0 + koff, &Vts[nxt][cid0 * 8]);
            gll16(vg1 + koff, &Vts[nxt][cid1 * 8]);
        }

        floatx4 s[2][4];
#pragma unroll
        for (int g = 0; g < 2; g++)
#pragma unroll
            for (int i = 0; i < 4; i++) s[g][i] = (floatx4){0.f, 0.f, 0.f, 0.f};
#pragma unroll
        for (int kk = 0; kk < 2; kk++) {
#pragma unroll
            for (int nt = 0; nt < 4; nt++) {
                const int slot = (kk * 4 + quad) ^ xo;
                short8 kf = *(const short8*)&Ks[cur][(nt * 16 + l15) * 64 + slot * 8];
                s[0][nt] = mfma16(kf, qf[0][kk], s[0][nt]);
                s[1][nt] = mfma16(kf, qf[1][kk], s[1][nt]);
            }
        }

        const int j = sp * 16 + t;   // global key tile index
#pragma unroll
        for (int g = 0; g < 2; g++) {
            const int tg = j - (qb * 2 + g);
            if (tg >= -1 && tg <= 1) {
                const int qg = q0 + g * 64 + wave * 16 + l15;
#pragma unroll
                for (int nt = 0; nt < 4; nt++) {
                    const int kgi = j * 64 + nt * 16 + quad * 4;
#pragma unroll
                    for (int r = 0; r < 4; r++) {
                        int dq = qg - (kgi + r);
                        int ad = dq < 0 ? -dq : dq;
                        s[g][nt][r] += mtab[ad];
                    }
                }
            }
        }

        short4v pb[2][4];
#pragma unroll
        for (int g = 0; g < 2; g++) {
#pragma unroll
            for (int nt = 0; nt < 4; nt++) {
                unsigned ur[4];
#pragma unroll
                for (int r = 0; r < 4; r++)
                    ur[r] = __float_as_uint(EXP2F(s[g][nt][r])) + 0x8000u;
                uint2 pk;
                pk.x = __builtin_amdgcn_perm(ur[1], ur[0], 0x07060302u);
                pk.y = __builtin_amdgcn_perm(ur[3], ur[2], 0x07060302u);
                pb[g][nt] = __builtin_bit_cast(short4v, pk);
            }
        }

#pragma unroll
        for (int kc = 0; kc < 4; kc++) {
#pragma unroll
            for (int nt = 0; nt < 4; nt++) {
                const int slot = (2 * kc + (quad >> 1)) ^ xo;
                short4v vf = *(const short4v*)
                    &Vts[cur][(nt * 16 + l15) * 64 + slot * 8 + (quad & 1) * 4];
                o[0][nt] = mfma16k16(vf, pb[0][kc], o[0][nt]);
                o[1][nt] = mfma16k16(vf, pb[1][kc], o[1][nt]);
            }
            ol[0] = mfma16k16(ones, pb[0][kc], ol[0]);
            ol[1] = mfma16k16(ones, pb[1][kc], ol[1]);
        }
    }

    ushort* Osp = sp ? O1 : O0;
#pragma unroll
    for (int g = 0; g < 2; g++) {
        const int qg = q0 + g * 64 + wave * 16 + l15;
        if (quad == 0)
            Lw[((size_t)(sp * 2 + bz) * NHEADS + h) * SEQ_L + qg] = ol[g][0];
        ushort* obase = Osp + ((size_t)bz * SEQ_L + qg) * D_MODEL + h * HDIM;
#pragma unroll
        for (int nt = 0; nt < 4; nt++) {
            ushort4v pk;
#pragma unroll
            for (int r = 0; r < 4; r++) pk[r] = f2bf(o[g][nt][r]);
            *(ushort4v*)(obase + nt * 16 + quad * 4) = pk;
        }
    }
}

// ---------------------------------------------------------------------------
// Kernel 2b: merge split-K partials: A = (O0 + O1) / (l0 + l1), bf16.
// ---------------------------------------------------------------------------
__global__ __launch_bounds__(256) void merge_attn(
    const ushort* __restrict__ O0, const ushort* __restrict__ O1,
    const float* __restrict__ Lw, ushort* __restrict__ Aout)
{
    const int gid = blockIdx.x * 256 + threadIdx.x;
    const int i = gid * 8;
    const int row = i >> 10;            // bz*2048 + q
    const int h   = (i >> 6) & 15;
    const int bz  = row >> 11, q = row & 2047;
    const int li  = (bz * NHEADS + h) * SEQ_L + q;
    const float linv = 1.f / (Lw[li] + Lw[2 * NHEADS * SEQ_L + li]);

    uint4 a = *(const uint4*)(O0 + i);
    uint4 b = *(const uint4*)(O1 + i);
    unsigned aw[4] = {a.x, a.y, a.z, a.w};
    unsigned bw[4] = {b.x, b.y, b.z, b.w};
    uint4 res;
    unsigned rw[4];
#pragma unroll
    for (int k = 0; k < 4; k++) {
        float alo = __uint_as_float(aw[k] << 16);
        float ahi = __uint_as_float(aw[k] & 0xFFFF0000u);
        float blo = __uint_as_float(bw[k] << 16);
        float bhi = __uint_as_float(bw[k] & 0xFFFF0000u);
        float lo = (alo + blo) * linv;
        float hi = (ahi + bhi) * linv;
        rw[k] = (unsigned)f2bf(lo) | ((unsigned)f2bf(hi) << 16);
    }
    res.x = rw[0]; res.y = rw[1]; res.z = rw[2]; res.w = rw[3];
    *(uint4*)(Aout + i) = res;
}

// ---------------------------------------------------------------------------
// Kernel 3: output projection. 64x64 tiles, grid 16x64 = 1024 blocks = 4/CU,
// single-buffered, SWAPPED operands -> C^T -> float4 stores.
// ---------------------------------------------------------------------------
__global__ __launch_bounds__(256, 4) void gemm_out(
    const ushort* __restrict__ A, const ushort* __restrict__ B,
    const float* __restrict__ bo, float* __restrict__ out)
{
    __shared__ ushort As[64 * 32];
    __shared__ ushort Bs[64 * 32];

    const int tid  = threadIdx.x;
    const int w    = tid >> 6;
    const int lane = tid & 63;
    const int l15  = lane & 15;
    const int quad = lane >> 4;

    const int bm = blockIdx.y * 64;
    const int bn = blockIdx.x * 64;

    const int r0 = w * 16 + (lane >> 2);   // 0..63
    const int c_ = lane & 3;
    const int g0 = c_ ^ ((r0 >> 1) & 3);

    const ushort* a0p = A + (size_t)(bm + r0) * 1024 + g0 * 8;
    const ushort* b0p = B + (size_t)(bn + r0) * 1024 + g0 * 8;
    ushort* lA0 = &As[r0 * 32 + c_ * 8];
    ushort* lB0 = &Bs[r0 * 32 + c_ * 8];

    const int cA = (quad ^ ((l15 >> 1) & 3)) * 8;

    floatx4 acc[4];
#pragma unroll
    for (int i = 0; i < 4; i++) acc[i] = (floatx4){0.f, 0.f, 0.f, 0.f};

    for (int k0 = 0; k0 < 1024; k0 += 32) {
        __syncthreads();
        gll16(a0p + k0, lA0);
        gll16(b0p + k0, lB0);
        __syncthreads();

        short8 bf = *(const short8*)&Bs[(w * 16 + l15) * 32 + cA];
#pragma unroll
        for (int mi = 0; mi < 4; mi++) {
            short8 af = *(const short8*)&As[(mi * 16 + l15) * 32 + cA];
            acc[mi] = mfma16(bf, af, acc[mi]);
        }
    }

    // D^T: lane holds x-row = l15, out-col = w*16 + quad*4 + r (consecutive)
    const int col0 = bn + w * 16 + quad * 4;
    const float4 bb4 = *(const float4*)&bo[col0];
#pragma unroll
    for (int mi = 0; mi < 4; mi++) {
        const int row = bm + mi * 16 + l15;
        float4 st;
        st.x = acc[mi][0] + bb4.x;
        st.y = acc[mi][1] + bb4.y;
        st.z = acc[mi][2] + bb4.z;
        st.w = acc[mi][3] + bb4.w;
        *(float4*)(out + (size_t)row * 1024 + col0) = st;
    }
}

// ---------------------------------------------------------------------------
extern "C" void kernel_launch(void* const* d_in, const int* in_sizes, int n_in,
                              void* d_out, int out_size, void* d_ws, size_t ws_size,
                              hipStream_t stream)
{
    const float* x   = (const float*)d_in[0];
    const float* Wq  = (const float*)d_in[1];
    const float* bq  = (const float*)d_in[2];
    const float* Wk  = (const float*)d_in[3];
    const float* bk  = (const float*)d_in[4];
    const float* Wv  = (const float*)d_in[5];
    const float* bv  = (const float*)d_in[6];
    const float* Wo  = (const float*)d_in[7];
    const float* bo  = (const float*)d_in[8];
    const float* lam = (const float*)d_in[9];
    float* out = (float*)d_out;

    const size_t NELEM = (size_t)NROWS * D_MODEL;   // 4194304
    ushort* Qw  = (ushort*)d_ws;                    //  8 MB
    ushort* Kw  = Qw + NELEM;                       //  8 MB
    ushort* Vw  = Kw + NELEM;                       //  8 MB
    ushort* O0  = Vw + NELEM;                       //  8 MB
    ushort* O1  = O0 + NELEM;                       //  8 MB
    ushort* XA  = O1 + NELEM;                       //  8 MB: xb, then merged A
    ushort* Wb3 = XA + NELEM;                       //  6 MB
    ushort* Wob = Wb3 + 3 * 1024 * 1024;            //  2 MB
    float*  Lw  = (float*)(Wob + 1024 * 1024);      //  512 KB

    dim3 gc(2048, 5);
    convert_bf16<<<gc, 256, 0, stream>>>(x, Wq, Wk, Wv, Wo, XA, Wb3, Wob);

    dim3 g1(3072 / 128, NROWS / 64);   // 24 x 64 = 1536 blocks
    gemm_qkv<<<g1, 256, 0, stream>>>(XA, Wb3, bq, bk, bv, Qw, Kw, Vw);

    dim3 g2(SEQ_L / 128, NHEADS, 4);   // z = batch*2 + key-split
    attn<<<g2, 256, 0, stream>>>(Qw, Kw, Vw, lam, O0, O1, Lw);

    merge_attn<<<NELEM / (256 * 8), 256, 0, stream>>>(O0, O1, Lw, XA);

    dim3 g3(1024 / 64, NROWS / 64);    // 16 x 64 = 1024 blocks
    gemm_out<<<g3, 256, 0, stream>>>(XA, Wob, bo, out);
}

// Round 8
// 217.726 us; speedup vs baseline: 1.7854x; 1.7854x over previous
//
#include <hip/hip_runtime.h>

#define D_MODEL 1024
#define SEQ_L   2048
#define NHEADS  16
#define HDIM    64
#define NROWS   4096   // B*L

// Q is pre-scaled by (1/sqrt(64)) * log2(e) so softmax uses exp2 directly.
#define QSCALE 0.18033688011112042f
#define LOG2E  1.4426950408889634f

#if __has_builtin(__builtin_amdgcn_exp2f)
#define EXP2F(x) __builtin_amdgcn_exp2f(x)
#else
#define EXP2F(x) __expf((x) * 0.6931471805599453f)
#endif

typedef __attribute__((ext_vector_type(8))) short short8;
typedef __attribute__((ext_vector_type(4))) short short4v;
typedef __attribute__((ext_vector_type(4))) float floatx4;
typedef __attribute__((ext_vector_type(4))) unsigned short ushort4v;
typedef unsigned short ushort;

static __device__ __forceinline__ ushort f2bf(float f) {
    unsigned int u = __float_as_uint(f);
    u += 0x7FFFu + ((u >> 16) & 1u);
    return (ushort)(u >> 16);
}

static __device__ __forceinline__ floatx4 mfma16(short8 a, short8 b, floatx4 c) {
    return __builtin_amdgcn_mfma_f32_16x16x32_bf16(a, b, c, 0, 0, 0);
}

static __device__ __forceinline__ floatx4 mfma16k16(short4v a, short4v b, floatx4 c) {
    return __builtin_amdgcn_mfma_f32_16x16x16bf16_1k(a, b, c, 0, 0, 0);
}

static __device__ __forceinline__ void store8bf(ushort* dst, float4 a, float4 b) {
    uint4 pk;
    pk.x = (unsigned)f2bf(a.x) | ((unsigned)f2bf(a.y) << 16);
    pk.y = (unsigned)f2bf(a.z) | ((unsigned)f2bf(a.w) << 16);
    pk.z = (unsigned)f2bf(b.x) | ((unsigned)f2bf(b.y) << 16);
    pk.w = (unsigned)f2bf(b.z) | ((unsigned)f2bf(b.w) << 16);
    *(uint4*)dst = pk;
}

// async global->LDS, 16B per lane. LDS dest must be wave-uniform base + lane*16.
static __device__ __forceinline__ void gll16(const ushort* g, ushort* l) {
    __builtin_amdgcn_global_load_lds(
        (const __attribute__((address_space(1))) unsigned int*)(const unsigned int*)g,
        (__attribute__((address_space(3))) unsigned int*)(unsigned int*)l,
        16, 0, 0);
}

// ---------------------------------------------------------------------------
// Kernel 0: fp32 -> bf16 conversion of x and weights.
// ---------------------------------------------------------------------------
__global__ __launch_bounds__(256) void convert_bf16(
    const float* __restrict__ x,
    const float* __restrict__ wq, const float* __restrict__ wk,
    const float* __restrict__ wv, const float* __restrict__ wo,
    ushort* __restrict__ xb, ushort* __restrict__ wb3, ushort* __restrict__ wob)
{
    const int seg = blockIdx.y;
    const float* src;
    ushort* dst;
    int n;
    if      (seg == 0) { src = x;  dst = xb;                n = 4194304; }
    else if (seg == 1) { src = wq; dst = wb3;               n = 1048576; }
    else if (seg == 2) { src = wk; dst = wb3 + 1048576;     n = 1048576; }
    else if (seg == 3) { src = wv; dst = wb3 + 2097152;     n = 1048576; }
    else               { src = wo; dst = wob;               n = 1048576; }
    const int i = (blockIdx.x * 256 + threadIdx.x) * 8;
    if (i >= n) return;
    float4 a = *(const float4*)(src + i);
    float4 b = *(const float4*)(src + i + 4);
    store8bf(dst + i, a, b);
}

// ---------------------------------------------------------------------------
// Kernel 1: fused QKV GEMM. 64(M)x128(N) tiles, grid 24x64 = 1536 blocks.
// __launch_bounds__(256,4): VGPR cap 128 — NO spill (R7's (256,6) forced 40
// VGPRs and spilled 693 MB to scratch). Compiler lands ~100 -> 4-5 waves/SIMD.
// Q/K use SWAPPED operand order (C^T) -> ushort4 epilogue stores.
// ---------------------------------------------------------------------------
__global__ __launch_bounds__(256, 4) void gemm_qkv(
    const ushort* __restrict__ A, const ushort* __restrict__ B,
    const float* __restrict__ bq, const float* __restrict__ bk,
    const float* __restrict__ bv,
    ushort* __restrict__ Qo, ushort* __restrict__ Ko, ushort* __restrict__ Vo)
{
    __shared__ ushort As[64 * 32];
    __shared__ ushort Bs[128 * 32];

    const int tid  = threadIdx.x;
    const int w    = tid >> 6;
    const int lane = tid & 63;
    const int l15  = lane & 15;
    const int quad = lane >> 4;

    const int bm = blockIdx.y * 64;     // x-row tile
    const int bn = blockIdx.x * 128;    // weight-col tile (0..3071)
    const int z  = blockIdx.x >> 3;     // 0=Q, 1=K, 2=V

    const int r0 = w * 16 + (lane >> 2);   // A row / B row round 0 (0..63)
    const int r1 = r0 + 64;                // B row round 1
    const int c_ = lane & 3;
    const int g0 = c_ ^ ((r0 >> 1) & 3);   // swizzled GLOBAL chunk
    const int g1 = c_ ^ ((r1 >> 1) & 3);

    const ushort* a0p = A + (size_t)(bm + r0) * 1024 + g0 * 8;
    const ushort* b0p = B + (size_t)(bn + r0) * 1024 + g0 * 8;
    const ushort* b1p = B + (size_t)(bn + r1) * 1024 + g1 * 8;
    ushort* lA0 = &As[r0 * 32 + c_ * 8];
    ushort* lB0 = &Bs[r0 * 32 + c_ * 8];
    ushort* lB1 = &Bs[r1 * 32 + c_ * 8];

    const int cA = (quad ^ ((l15 >> 1) & 3)) * 8;   // swizzled read chunk

    floatx4 acc[4][2];
#pragma unroll
    for (int i = 0; i < 4; i++)
#pragma unroll
        for (int j = 0; j < 2; j++) acc[i][j] = (floatx4){0.f, 0.f, 0.f, 0.f};

    for (int k0 = 0; k0 < 1024; k0 += 32) {
        __syncthreads();
        gll16(a0p + k0, lA0);
        gll16(b0p + k0, lB0);
        gll16(b1p + k0, lB1);
        __syncthreads();

        short8 af[4], bf[2];
#pragma unroll
        for (int mi = 0; mi < 4; mi++)
            af[mi] = *(const short8*)&As[(mi * 16 + l15) * 32 + cA];
#pragma unroll
        for (int ni = 0; ni < 2; ni++)
            bf[ni] = *(const short8*)&Bs[(w * 32 + ni * 16 + l15) * 32 + cA];
        if (z == 2) {
#pragma unroll
            for (int mi = 0; mi < 4; mi++)
#pragma unroll
                for (int ni = 0; ni < 2; ni++)
                    acc[mi][ni] = mfma16(af[mi], bf[ni], acc[mi][ni]);
        } else {
#pragma unroll
            for (int mi = 0; mi < 4; mi++)
#pragma unroll
                for (int ni = 0; ni < 2; ni++)
                    acc[mi][ni] = mfma16(bf[ni], af[mi], acc[mi][ni]);
        }
    }

    const int cwbase = bn & 1023;     // weight-col base within this matrix
    if (z == 2) {
        // ----- V epilogue (normal): lane col = l15, rows quad*4+r -> V^T store
#pragma unroll
        for (int ni = 0; ni < 2; ni++) {
            const int within = cwbase + w * 32 + ni * 16 + l15;
            const int h  = within >> 6;
            const int hd = within & 63;
            const float bvl = bv[within];
#pragma unroll
            for (int mi = 0; mi < 4; mi++) {
                const int row = bm + mi * 16 + quad * 4;
                const int bb = row >> 11, li = row & 2047;
                ushort4v pk;
#pragma unroll
                for (int r = 0; r < 4; r++) pk[r] = f2bf(acc[mi][ni][r] + bvl);
                *(ushort4v*)(Vo + ((size_t)(bb * NHEADS + h) * HDIM + hd) * SEQ_L + li) = pk;
            }
        }
    } else {
        // ----- Q/K epilogue (C^T): lane holds 4 consecutive weight cols -----
        const float* bias = z ? bk : bq;
        const float scale = z ? 1.0f : QSCALE;
        ushort* outp = z ? Ko : Qo;
#pragma unroll
        for (int ni = 0; ni < 2; ni++) {
            const int colw = cwbase + w * 32 + ni * 16 + quad * 4;
            const int h   = colw >> 6;
            const int hd0 = colw & 63;
            const float4 bb4 = *(const float4*)&bias[colw];
#pragma unroll
            for (int mi = 0; mi < 4; mi++) {
                const int row = bm + mi * 16 + l15;
                const int bb = row >> 11, li = row & 2047;
                ushort4v pk;
                pk[0] = f2bf((acc[mi][ni][0] + bb4.x) * scale);
                pk[1] = f2bf((acc[mi][ni][1] + bb4.y) * scale);
                pk[2] = f2bf((acc[mi][ni][2] + bb4.z) * scale);
                pk[3] = f2bf((acc[mi][ni][3] + bb4.w) * scale);
                *(ushort4v*)(outp + ((size_t)(bb * NHEADS + h) * SEQ_L + li) * HDIM + hd0) = pk;
            }
        }
    }
}

// ---------------------------------------------------------------------------
// Kernel 2: flash attention, S^T formulation, 128-query blocks, 2-way K-split.
// ---------------------------------------------------------------------------
__global__ __launch_bounds__(256, 4) void attn(
    const ushort* __restrict__ Q,
    const ushort* __restrict__ K,
    const ushort* __restrict__ Vt,
    const float* __restrict__ lam,
    ushort* __restrict__ O0, ushort* __restrict__ O1,
    float* __restrict__ Lw)
{
    __shared__ float mtab[128];
    __shared__ ushort Ks[2][64 * 64];
    __shared__ ushort Vts[2][64 * 64];

    const int tid  = threadIdx.x;
    const int wave = tid >> 6;
    const int lane = tid & 63;
    const int l15  = lane & 15;
    const int quad = lane >> 4;

    const int qb = blockIdx.x;           // 0..15
    const int h  = blockIdx.y;
    const int zz = blockIdx.z;           // 0..3
    const int bz = zz >> 1;
    const int sp = zz & 1;               // key split
    const int bh = bz * NHEADS + h;
    const int q0 = qb * 128;
    const int kb = sp * 1024;            // key base

    const float lambda = *lam;
    if (tid < 128) {
        float d  = (float)tid;
        float e1 = (d - 1.f) * (d - 1.f);
        float e2 = (d - 30.f) * (d - 30.f);
        mtab[tid] = LOG2E * lambda *
                    (0.8f * __expf(-2.0f * e1) + 0.4f * __expf(-0.125f * e2));
    }

    const ushort* qp =
        Q + ((size_t)bh * SEQ_L + q0 + wave * 16 + l15) * HDIM + quad * 8;
    short8 qf[2][2];
    qf[0][0] = *(const short8*)qp;
    qf[0][1] = *(const short8*)(qp + 32);
    qf[1][0] = *(const short8*)(qp + 64 * HDIM);
    qf[1][1] = *(const short8*)(qp + 64 * HDIM + 32);

    const ushort* kbase = K  + ((size_t)bh * SEQ_L) * HDIM;
    const ushort* vbase = Vt + ((size_t)bh * HDIM) * SEQ_L;

    const int cid0 = tid, cid1 = 256 + tid;
    const int row0 = cid0 >> 3, row1 = cid1 >> 3;
    const int cl0  = (cid0 & 7) ^ (row0 & 7);
    const int cl1  = (cid1 & 7) ^ (row1 & 7);
    const ushort* kg0 = kbase + (size_t)(kb + row0) * HDIM + cl0 * 8;
    const ushort* kg1 = kbase + (size_t)(kb + row1) * HDIM + cl1 * 8;
    const ushort* vg0 = vbase + (size_t)row0 * SEQ_L + kb + cl0 * 8;
    const ushort* vg1 = vbase + (size_t)row1 * SEQ_L + kb + cl1 * 8;

    floatx4 o[2][4];
#pragma unroll
    for (int g = 0; g < 2; g++)
#pragma unroll
        for (int i = 0; i < 4; i++) o[g][i] = (floatx4){0.f, 0.f, 0.f, 0.f};
    floatx4 ol[2];
    ol[0] = (floatx4){0.f, 0.f, 0.f, 0.f};
    ol[1] = (floatx4){0.f, 0.f, 0.f, 0.f};

    short4v ones;
    ones[0] = 0x3F80; ones[1] = 0x3F80; ones[2] = 0x3F80; ones[3] = 0x3F80;

    gll16(kg0, &Ks[0][cid0 * 8]);
    gll16(kg1, &Ks[0][cid1 * 8]);
    gll16(vg0, &Vts[0][cid0 * 8]);
    gll16(vg1, &Vts[0][cid1 * 8]);

    const int xo = l15 & 7;

    for (int t = 0; t < 16; t++) {
        const int cur = t & 1;
        __syncthreads();
        if (t + 1 < 16) {
            const int nxt = cur ^ 1;
            const int koff = (t + 1) * 64;
            gll16(kg0 + (size_t)koff * HDIM, &Ks[nxt][cid0 * 8]);
            gll16(kg1 + (size_t)koff * HDIM, &Ks[nxt][cid1 * 8]);
            gll16(vg0 + koff, &Vts[nxt][cid0 * 8]);
            gll16(vg1 + koff, &Vts[nxt][cid1 * 8]);
        }

        floatx4 s[2][4];
#pragma unroll
        for (int g = 0; g < 2; g++)
#pragma unroll
            for (int i = 0; i < 4; i++) s[g][i] = (floatx4){0.f, 0.f, 0.f, 0.f};
#pragma unroll
        for (int kk = 0; kk < 2; kk++) {
#pragma unroll
            for (int nt = 0; nt < 4; nt++) {
                const int slot = (kk * 4 + quad) ^ xo;
                short8 kf = *(const short8*)&Ks[cur][(nt * 16 + l15) * 64 + slot * 8];
                s[0][nt] = mfma16(kf, qf[0][kk], s[0][nt]);
                s[1][nt] = mfma16(kf, qf[1][kk], s[1][nt]);
            }
        }

        const int j = sp * 16 + t;   // global key tile index
#pragma unroll
        for (int g = 0; g < 2; g++) {
            const int tg = j - (qb * 2 + g);
            if (tg >= -1 && tg <= 1) {
                const int qg = q0 + g * 64 + wave * 16 + l15;
#pragma unroll
                for (int nt = 0; nt < 4; nt++) {
                    const int kgi = j * 64 + nt * 16 + quad * 4;
#pragma unroll
                    for (int r = 0; r < 4; r++) {
                        int dq = qg - (kgi + r);
                        int ad = dq < 0 ? -dq : dq;
                        s[g][nt][r] += mtab[ad];
                    }
                }
            }
        }

        short4v pb[2][4];
#pragma unroll
        for (int g = 0; g < 2; g++) {
#pragma unroll
            for (int nt = 0; nt < 4; nt++) {
                unsigned ur[4];
#pragma unroll
                for (int r = 0; r < 4; r++)
                    ur[r] = __float_as_uint(EXP2F(s[g][nt][r])) + 0x8000u;
                uint2 pk;
                pk.x = __builtin_amdgcn_perm(ur[1], ur[0], 0x07060302u);
                pk.y = __builtin_amdgcn_perm(ur[3], ur[2], 0x07060302u);
                pb[g][nt] = __builtin_bit_cast(short4v, pk);
            }
        }

#pragma unroll
        for (int kc = 0; kc < 4; kc++) {
#pragma unroll
            for (int nt = 0; nt < 4; nt++) {
                const int slot = (2 * kc + (quad >> 1)) ^ xo;
                short4v vf = *(const short4v*)
                    &Vts[cur][(nt * 16 + l15) * 64 + slot * 8 + (quad & 1) * 4];
                o[0][nt] = mfma16k16(vf, pb[0][kc], o[0][nt]);
                o[1][nt] = mfma16k16(vf, pb[1][kc], o[1][nt]);
            }
            ol[0] = mfma16k16(ones, pb[0][kc], ol[0]);
            ol[1] = mfma16k16(ones, pb[1][kc], ol[1]);
        }
    }

    ushort* Osp = sp ? O1 : O0;
#pragma unroll
    for (int g = 0; g < 2; g++) {
        const int qg = q0 + g * 64 + wave * 16 + l15;
        if (quad == 0)
            Lw[((size_t)(sp * 2 + bz) * NHEADS + h) * SEQ_L + qg] = ol[g][0];
        ushort* obase = Osp + ((size_t)bz * SEQ_L + qg) * D_MODEL + h * HDIM;
#pragma unroll
        for (int nt = 0; nt < 4; nt++) {
            ushort4v pk;
#pragma unroll
            for (int r = 0; r < 4; r++) pk[r] = f2bf(o[g][nt][r]);
            *(ushort4v*)(obase + nt * 16 + quad * 4) = pk;
        }
    }
}

// ---------------------------------------------------------------------------
// Kernel 2b: merge split-K partials: A = (O0 + O1) / (l0 + l1), bf16.
// ---------------------------------------------------------------------------
__global__ __launch_bounds__(256) void merge_attn(
    const ushort* __restrict__ O0, const ushort* __restrict__ O1,
    const float* __restrict__ Lw, ushort* __restrict__ Aout)
{
    const int gid = blockIdx.x * 256 + threadIdx.x;
    const int i = gid * 8;
    const int row = i >> 10;            // bz*2048 + q
    const int h   = (i >> 6) & 15;
    const int bz  = row >> 11, q = row & 2047;
    const int li  = (bz * NHEADS + h) * SEQ_L + q;
    const float linv = 1.f / (Lw[li] + Lw[2 * NHEADS * SEQ_L + li]);

    uint4 a = *(const uint4*)(O0 + i);
    uint4 b = *(const uint4*)(O1 + i);
    unsigned aw[4] = {a.x, a.y, a.z, a.w};
    unsigned bw[4] = {b.x, b.y, b.z, b.w};
    uint4 res;
    unsigned rw[4];
#pragma unroll
    for (int k = 0; k < 4; k++) {
        float alo = __uint_as_float(aw[k] << 16);
        float ahi = __uint_as_float(aw[k] & 0xFFFF0000u);
        float blo = __uint_as_float(bw[k] << 16);
        float bhi = __uint_as_float(bw[k] & 0xFFFF0000u);
        float lo = (alo + blo) * linv;
        float hi = (ahi + bhi) * linv;
        rw[k] = (unsigned)f2bf(lo) | ((unsigned)f2bf(hi) << 16);
    }
    res.x = rw[0]; res.y = rw[1]; res.z = rw[2]; res.w = rw[3];
    *(uint4*)(Aout + i) = res;
}

// ---------------------------------------------------------------------------
// Kernel 3: output projection. 64x64 tiles, grid 16x64 = 1024 blocks = 4/CU,
// single-buffered, SWAPPED operands -> C^T -> float4 stores.
// ---------------------------------------------------------------------------
__global__ __launch_bounds__(256, 4) void gemm_out(
    const ushort* __restrict__ A, const ushort* __restrict__ B,
    const float* __restrict__ bo, float* __restrict__ out)
{
    __shared__ ushort As[64 * 32];
    __shared__ ushort Bs[64 * 32];

    const int tid  = threadIdx.x;
    const int w    = tid >> 6;
    const int lane = tid & 63;
    const int l15  = lane & 15;
    const int quad = lane >> 4;

    const int bm = blockIdx.y * 64;
    const int bn = blockIdx.x * 64;

    const int r0 = w * 16 + (lane >> 2);   // 0..63
    const int c_ = lane & 3;
    const int g0 = c_ ^ ((r0 >> 1) & 3);

    const ushort* a0p = A + (size_t)(bm + r0) * 1024 + g0 * 8;
    const ushort* b0p = B + (size_t)(bn + r0) * 1024 + g0 * 8;
    ushort* lA0 = &As[r0 * 32 + c_ * 8];
    ushort* lB0 = &Bs[r0 * 32 + c_ * 8];

    const int cA = (quad ^ ((l15 >> 1) & 3)) * 8;

    floatx4 acc[4];
#pragma unroll
    for (int i = 0; i < 4; i++) acc[i] = (floatx4){0.f, 0.f, 0.f, 0.f};

    for (int k0 = 0; k0 < 1024; k0 += 32) {
        __syncthreads();
        gll16(a0p + k0, lA0);
        gll16(b0p + k0, lB0);
        __syncthreads();

        short8 bf = *(const short8*)&Bs[(w * 16 + l15) * 32 + cA];
#pragma unroll
        for (int mi = 0; mi < 4; mi++) {
            short8 af = *(const short8*)&As[(mi * 16 + l15) * 32 + cA];
            acc[mi] = mfma16(bf, af, acc[mi]);
        }
    }

    // D^T: lane holds x-row = l15, out-col = w*16 + quad*4 + r (consecutive)
    const int col0 = bn + w * 16 + quad * 4;
    const float4 bb4 = *(const float4*)&bo[col0];
#pragma unroll
    for (int mi = 0; mi < 4; mi++) {
        const int row = bm + mi * 16 + l15;
        float4 st;
        st.x = acc[mi][0] + bb4.x;
        st.y = acc[mi][1] + bb4.y;
        st.z = acc[mi][2] + bb4.z;
        st.w = acc[mi][3] + bb4.w;
        *(float4*)(out + (size_t)row * 1024 + col0) = st;
    }
}

// ---------------------------------------------------------------------------
extern "C" void kernel_launch(void* const* d_in, const int* in_sizes, int n_in,
                              void* d_out, int out_size, void* d_ws, size_t ws_size,
                              hipStream_t stream)
{
    const float* x   = (const float*)d_in[0];
    const float* Wq  = (const float*)d_in[1];
    const float* bq  = (const float*)d_in[2];
    const float* Wk  = (const float*)d_in[3];
    const float* bk  = (const float*)d_in[4];
    const float* Wv  = (const float*)d_in[5];
    const float* bv  = (const float*)d_in[6];
    const float* Wo  = (const float*)d_in[7];
    const float* bo  = (const float*)d_in[8];
    const float* lam = (const float*)d_in[9];
    float* out = (float*)d_out;

    const size_t NELEM = (size_t)NROWS * D_MODEL;   // 4194304
    ushort* Qw  = (ushort*)d_ws;                    //  8 MB
    ushort* Kw  = Qw + NELEM;                       //  8 MB
    ushort* Vw  = Kw + NELEM;                       //  8 MB
    ushort* O0  = Vw + NELEM;                       //  8 MB
    ushort* O1  = O0 + NELEM;                       //  8 MB
    ushort* XA  = O1 + NELEM;                       //  8 MB: xb, then merged A
    ushort* Wb3 = XA + NELEM;                       //  6 MB
    ushort* Wob = Wb3 + 3 * 1024 * 1024;            //  2 MB
    float*  Lw  = (float*)(Wob + 1024 * 1024);      //  512 KB

    dim3 gc(2048, 5);
    convert_bf16<<<gc, 256, 0, stream>>>(x, Wq, Wk, Wv, Wo, XA, Wb3, Wob);

    dim3 g1(3072 / 128, NROWS / 64);   // 24 x 64 = 1536 blocks
    gemm_qkv<<<g1, 256, 0, stream>>>(XA, Wb3, bq, bk, bv, Qw, Kw, Vw);

    dim3 g2(SEQ_L / 128, NHEADS, 4);   // z = batch*2 + key-split
    attn<<<g2, 256, 0, stream>>>(Qw, Kw, Vw, lam, O0, O1, Lw);

    merge_attn<<<NELEM / (256 * 8), 256, 0, stream>>>(O0, O1, Lw, XA);

    dim3 g3(1024 / 64, NROWS / 64);    // 16 x 64 = 1024 blocks
    gemm_out<<<g3, 256, 0, stream>>>(XA, Wob, bo, out);
}

// Round 9
// 199.235 us; speedup vs baseline: 1.9511x; 1.0928x over previous
//
#include <hip/hip_runtime.h>

#define D_MODEL 1024
#define SEQ_L   2048
#define NHEADS  16
#define HDIM    64
#define NROWS   4096   // B*L

// Q is pre-scaled by (1/sqrt(64)) * log2(e) so softmax uses exp2 directly.
#define QSCALE 0.18033688011112042f
#define LOG2E  1.4426950408889634f

#if __has_builtin(__builtin_amdgcn_exp2f)
#define EXP2F(x) __builtin_amdgcn_exp2f(x)
#else
#define EXP2F(x) __expf((x) * 0.6931471805599453f)
#endif

typedef __attribute__((ext_vector_type(8))) short short8;
typedef __attribute__((ext_vector_type(4))) short short4v;
typedef __attribute__((ext_vector_type(4))) float floatx4;
typedef __attribute__((ext_vector_type(4))) unsigned short ushort4v;
typedef unsigned short ushort;

static __device__ __forceinline__ ushort f2bf(float f) {
    unsigned int u = __float_as_uint(f);
    u += 0x7FFFu + ((u >> 16) & 1u);
    return (ushort)(u >> 16);
}

static __device__ __forceinline__ floatx4 mfma16(short8 a, short8 b, floatx4 c) {
    return __builtin_amdgcn_mfma_f32_16x16x32_bf16(a, b, c, 0, 0, 0);
}

static __device__ __forceinline__ floatx4 mfma16k16(short4v a, short4v b, floatx4 c) {
    return __builtin_amdgcn_mfma_f32_16x16x16bf16_1k(a, b, c, 0, 0, 0);
}

static __device__ __forceinline__ void store8bf(ushort* dst, float4 a, float4 b) {
    uint4 pk;
    pk.x = (unsigned)f2bf(a.x) | ((unsigned)f2bf(a.y) << 16);
    pk.y = (unsigned)f2bf(a.z) | ((unsigned)f2bf(a.w) << 16);
    pk.z = (unsigned)f2bf(b.x) | ((unsigned)f2bf(b.y) << 16);
    pk.w = (unsigned)f2bf(b.z) | ((unsigned)f2bf(b.w) << 16);
    *(uint4*)dst = pk;
}

// async global->LDS, 16B per lane.
static __device__ __forceinline__ void gll16(const ushort* g, ushort* l) {
    __builtin_amdgcn_global_load_lds(
        (const __attribute__((address_space(1))) unsigned int*)(const unsigned int*)g,
        (__attribute__((address_space(3))) unsigned int*)(unsigned int*)l,
        16, 0, 0);
}

// ---------------------------------------------------------------------------
// Kernel 0: fp32 -> bf16 conversion of x and weights.
// ---------------------------------------------------------------------------
__global__ __launch_bounds__(256) void convert_bf16(
    const float* __restrict__ x,
    const float* __restrict__ wq, const float* __restrict__ wk,
    const float* __restrict__ wv, const float* __restrict__ wo,
    ushort* __restrict__ xb, ushort* __restrict__ wb3, ushort* __restrict__ wob)
{
    const int seg = blockIdx.y;
    const float* src;
    ushort* dst;
    int n;
    if      (seg == 0) { src = x;  dst = xb;                n = 4194304; }
    else if (seg == 1) { src = wq; dst = wb3;               n = 1048576; }
    else if (seg == 2) { src = wk; dst = wb3 + 1048576;     n = 1048576; }
    else if (seg == 3) { src = wv; dst = wb3 + 2097152;     n = 1048576; }
    else               { src = wo; dst = wob;               n = 1048576; }
    const int i = (blockIdx.x * 256 + threadIdx.x) * 8;
    if (i >= n) return;
    float4 a = *(const float4*)(src + i);
    float4 b = *(const float4*)(src + i + 4);
    store8bf(dst + i, a, b);
}

// ---------------------------------------------------------------------------
// Kernel 1: fused QKV GEMM. 64(M)x128(N)xBK64 tiles, grid 24x64 = 1536 blocks.
// BK=64: 16 barriers total (was 32), 16 MFMA per wave-iter per drain.
// LDS 24 KB. XOR slot swizzle c^(row&7) -> 2-way LDS reads (free).
// Q/K use SWAPPED operand order (C^T) -> ushort4 epilogue stores.
// ---------------------------------------------------------------------------
__global__ __launch_bounds__(256, 4) void gemm_qkv(
    const ushort* __restrict__ A, const ushort* __restrict__ B,
    const float* __restrict__ bq, const float* __restrict__ bk,
    const float* __restrict__ bv,
    ushort* __restrict__ Qo, ushort* __restrict__ Ko, ushort* __restrict__ Vo)
{
    __shared__ ushort As[64 * 64];    //  8 KB
    __shared__ ushort Bs[128 * 64];   // 16 KB

    const int tid  = threadIdx.x;
    const int w    = tid >> 6;
    const int lane = tid & 63;
    const int l15  = lane & 15;
    const int quad = lane >> 4;

    const int bm = blockIdx.y * 64;     // x-row tile
    const int bn = blockIdx.x * 128;    // weight-col tile (0..3071)
    const int z  = blockIdx.x >> 3;     // 0=Q, 1=K, 2=V

    // --- staging map: chunk ci -> row=ci>>3, slot=ci&7, global chunk g=slot^(row&7)
    const int ciA0 = tid,        ciA1 = tid + 256;          // As: 512 chunks
    const int rA0 = ciA0 >> 3,   rA1 = ciA1 >> 3;
    const int sA0i = ciA0 & 7,   sA1i = ciA1 & 7;
    const ushort* aP0 = A + (size_t)(bm + rA0) * 1024 + (sA0i ^ (rA0 & 7)) * 8;
    const ushort* aP1 = A + (size_t)(bm + rA1) * 1024 + (sA1i ^ (rA1 & 7)) * 8;
    ushort* lA0 = &As[rA0 * 64 + sA0i * 8];
    ushort* lA1 = &As[rA1 * 64 + sA1i * 8];

    const ushort* bP[4];
    ushort* lB[4];
#pragma unroll
    for (int p = 0; p < 4; p++) {                            // Bs: 1024 chunks
        const int ci = tid + p * 256;
        const int r = ci >> 3, s = ci & 7;
        bP[p] = B + (size_t)(bn + r) * 1024 + (s ^ (r & 7)) * 8;
        lB[p] = &Bs[r * 64 + s * 8];
    }

    const int x7 = l15 & 7;

    floatx4 acc[4][2];
#pragma unroll
    for (int i = 0; i < 4; i++)
#pragma unroll
        for (int j = 0; j < 2; j++) acc[i][j] = (floatx4){0.f, 0.f, 0.f, 0.f};

    for (int k0 = 0; k0 < 1024; k0 += 64) {
        __syncthreads();
        gll16(aP0 + k0, lA0);
        gll16(aP1 + k0, lA1);
#pragma unroll
        for (int p = 0; p < 4; p++) gll16(bP[p] + k0, lB[p]);
        __syncthreads();

#pragma unroll
        for (int kk = 0; kk < 2; kk++) {
            const int slot = ((kk * 4 + quad) ^ x7) * 8;
            short8 af[4], bf[2];
#pragma unroll
            for (int mi = 0; mi < 4; mi++)
                af[mi] = *(const short8*)&As[(mi * 16 + l15) * 64 + slot];
#pragma unroll
            for (int ni = 0; ni < 2; ni++)
                bf[ni] = *(const short8*)&Bs[(w * 32 + ni * 16 + l15) * 64 + slot];
            if (z == 2) {
#pragma unroll
                for (int mi = 0; mi < 4; mi++)
#pragma unroll
                    for (int ni = 0; ni < 2; ni++)
                        acc[mi][ni] = mfma16(af[mi], bf[ni], acc[mi][ni]);
            } else {
#pragma unroll
                for (int mi = 0; mi < 4; mi++)
#pragma unroll
                    for (int ni = 0; ni < 2; ni++)
                        acc[mi][ni] = mfma16(bf[ni], af[mi], acc[mi][ni]);
            }
        }
    }

    const int cwbase = bn & 1023;     // weight-col base within this matrix
    if (z == 2) {
        // ----- V epilogue (normal): lane col = l15, rows quad*4+r -> V^T store
#pragma unroll
        for (int ni = 0; ni < 2; ni++) {
            const int within = cwbase + w * 32 + ni * 16 + l15;
            const int h  = within >> 6;
            const int hd = within & 63;
            const float bvl = bv[within];
#pragma unroll
            for (int mi = 0; mi < 4; mi++) {
                const int row = bm + mi * 16 + quad * 4;
                const int bb = row >> 11, li = row & 2047;
                ushort4v pk;
#pragma unroll
                for (int r = 0; r < 4; r++) pk[r] = f2bf(acc[mi][ni][r] + bvl);
                *(ushort4v*)(Vo + ((size_t)(bb * NHEADS + h) * HDIM + hd) * SEQ_L + li) = pk;
            }
        }
    } else {
        // ----- Q/K epilogue (C^T): lane holds 4 consecutive weight cols -----
        const float* bias = z ? bk : bq;
        const float scale = z ? 1.0f : QSCALE;
        ushort* outp = z ? Ko : Qo;
#pragma unroll
        for (int ni = 0; ni < 2; ni++) {
            const int colw = cwbase + w * 32 + ni * 16 + quad * 4;
            const int h   = colw >> 6;
            const int hd0 = colw & 63;
            const float4 bb4 = *(const float4*)&bias[colw];
#pragma unroll
            for (int mi = 0; mi < 4; mi++) {
                const int row = bm + mi * 16 + l15;
                const int bb = row >> 11, li = row & 2047;
                ushort4v pk;
                pk[0] = f2bf((acc[mi][ni][0] + bb4.x) * scale);
                pk[1] = f2bf((acc[mi][ni][1] + bb4.y) * scale);
                pk[2] = f2bf((acc[mi][ni][2] + bb4.z) * scale);
                pk[3] = f2bf((acc[mi][ni][3] + bb4.w) * scale);
                *(ushort4v*)(outp + ((size_t)(bb * NHEADS + h) * SEQ_L + li) * HDIM + hd0) = pk;
            }
        }
    }
}

// ---------------------------------------------------------------------------
// Kernel 2: flash attention, S^T formulation, 128-query blocks, 2-way K-split.
// ---------------------------------------------------------------------------
__global__ __launch_bounds__(256, 4) void attn(
    const ushort* __restrict__ Q,
    const ushort* __restrict__ K,
    const ushort* __restrict__ Vt,
    const float* __restrict__ lam,
    ushort* __restrict__ O0, ushort* __restrict__ O1,
    float* __restrict__ Lw)
{
    __shared__ float mtab[128];
    __shared__ ushort Ks[2][64 * 64];
    __shared__ ushort Vts[2][64 * 64];

    const int tid  = threadIdx.x;
    const int wave = tid >> 6;
    const int lane = tid & 63;
    const int l15  = lane & 15;
    const int quad = lane >> 4;

    const int qb = blockIdx.x;           // 0..15
    const int h  = blockIdx.y;
    const int zz = blockIdx.z;           // 0..3
    const int bz = zz >> 1;
    const int sp = zz & 1;               // key split
    const int bh = bz * NHEADS + h;
    const int q0 = qb * 128;
    const int kb = sp * 1024;            // key base

    const float lambda = *lam;
    if (tid < 128) {
        float d  = (float)tid;
        float e1 = (d - 1.f) * (d - 1.f);
        float e2 = (d - 30.f) * (d - 30.f);
        mtab[tid] = LOG2E * lambda *
                    (0.8f * __expf(-2.0f * e1) + 0.4f * __expf(-0.125f * e2));
    }

    const ushort* qp =
        Q + ((size_t)bh * SEQ_L + q0 + wave * 16 + l15) * HDIM + quad * 8;
    short8 qf[2][2];
    qf[0][0] = *(const short8*)qp;
    qf[0][1] = *(const short8*)(qp + 32);
    qf[1][0] = *(const short8*)(qp + 64 * HDIM);
    qf[1][1] = *(const short8*)(qp + 64 * HDIM + 32);

    const ushort* kbase = K  + ((size_t)bh * SEQ_L) * HDIM;
    const ushort* vbase = Vt + ((size_t)bh * HDIM) * SEQ_L;

    const int cid0 = tid, cid1 = 256 + tid;
    const int row0 = cid0 >> 3, row1 = cid1 >> 3;
    const int cl0  = (cid0 & 7) ^ (row0 & 7);
    const int cl1  = (cid1 & 7) ^ (row1 & 7);
    const ushort* kg0 = kbase + (size_t)(kb + row0) * HDIM + cl0 * 8;
    const ushort* kg1 = kbase + (size_t)(kb + row1) * HDIM + cl1 * 8;
    const ushort* vg0 = vbase + (size_t)row0 * SEQ_L + kb + cl0 * 8;
    const ushort* vg1 = vbase + (size_t)row1 * SEQ_L + kb + cl1 * 8;

    floatx4 o[2][4];
#pragma unroll
    for (int g = 0; g < 2; g++)
#pragma unroll
        for (int i = 0; i < 4; i++) o[g][i] = (floatx4){0.f, 0.f, 0.f, 0.f};
    floatx4 ol[2];
    ol[0] = (floatx4){0.f, 0.f, 0.f, 0.f};
    ol[1] = (floatx4){0.f, 0.f, 0.f, 0.f};

    short4v ones;
    ones[0] = 0x3F80; ones[1] = 0x3F80; ones[2] = 0x3F80; ones[3] = 0x3F80;

    gll16(kg0, &Ks[0][cid0 * 8]);
    gll16(kg1, &Ks[0][cid1 * 8]);
    gll16(vg0, &Vts[0][cid0 * 8]);
    gll16(vg1, &Vts[0][cid1 * 8]);

    const int xo = l15 & 7;

    for (int t = 0; t < 16; t++) {
        const int cur = t & 1;
        __syncthreads();
        if (t + 1 < 16) {
            const int nxt = cur ^ 1;
            const int koff = (t + 1) * 64;
            gll16(kg0 + (size_t)koff * HDIM, &Ks[nxt][cid0 * 8]);
            gll16(kg1 + (size_t)koff * HDIM, &Ks[nxt][cid1 * 8]);
            gll16(vg0 + koff, &Vts[nxt][cid0 * 8]);
            gll16(vg1 + koff, &Vts[nxt][cid1 * 8]);
        }

        floatx4 s[2][4];
#pragma unroll
        for (int g = 0; g < 2; g++)
#pragma unroll
            for (int i = 0; i < 4; i++) s[g][i] = (floatx4){0.f, 0.f, 0.f, 0.f};
#pragma unroll
        for (int kk = 0; kk < 2; kk++) {
#pragma unroll
            for (int nt = 0; nt < 4; nt++) {
                const int slot = (kk * 4 + quad) ^ xo;
                short8 kf = *(const short8*)&Ks[cur][(nt * 16 + l15) * 64 + slot * 8];
                s[0][nt] = mfma16(kf, qf[0][kk], s[0][nt]);
                s[1][nt] = mfma16(kf, qf[1][kk], s[1][nt]);
            }
        }

        const int j = sp * 16 + t;   // global key tile index
#pragma unroll
        for (int g = 0; g < 2; g++) {
            const int tg = j - (qb * 2 + g);
            if (tg >= -1 && tg <= 1) {
                const int qg = q0 + g * 64 + wave * 16 + l15;
#pragma unroll
                for (int nt = 0; nt < 4; nt++) {
                    const int kgi = j * 64 + nt * 16 + quad * 4;
#pragma unroll
                    for (int r = 0; r < 4; r++) {
                        int dq = qg - (kgi + r);
                        int ad = dq < 0 ? -dq : dq;
                        s[g][nt][r] += mtab[ad];
                    }
                }
            }
        }

        short4v pb[2][4];
#pragma unroll
        for (int g = 0; g < 2; g++) {
#pragma unroll
            for (int nt = 0; nt < 4; nt++) {
                unsigned ur[4];
#pragma unroll
                for (int r = 0; r < 4; r++)
                    ur[r] = __float_as_uint(EXP2F(s[g][nt][r])) + 0x8000u;
                uint2 pk;
                pk.x = __builtin_amdgcn_perm(ur[1], ur[0], 0x07060302u);
                pk.y = __builtin_amdgcn_perm(ur[3], ur[2], 0x07060302u);
                pb[g][nt] = __builtin_bit_cast(short4v, pk);
            }
        }

#pragma unroll
        for (int kc = 0; kc < 4; kc++) {
#pragma unroll
            for (int nt = 0; nt < 4; nt++) {
                const int slot = (2 * kc + (quad >> 1)) ^ xo;
                short4v vf = *(const short4v*)
                    &Vts[cur][(nt * 16 + l15) * 64 + slot * 8 + (quad & 1) * 4];
                o[0][nt] = mfma16k16(vf, pb[0][kc], o[0][nt]);
                o[1][nt] = mfma16k16(vf, pb[1][kc], o[1][nt]);
            }
            ol[0] = mfma16k16(ones, pb[0][kc], ol[0]);
            ol[1] = mfma16k16(ones, pb[1][kc], ol[1]);
        }
    }

    ushort* Osp = sp ? O1 : O0;
#pragma unroll
    for (int g = 0; g < 2; g++) {
        const int qg = q0 + g * 64 + wave * 16 + l15;
        if (quad == 0)
            Lw[((size_t)(sp * 2 + bz) * NHEADS + h) * SEQ_L + qg] = ol[g][0];
        ushort* obase = Osp + ((size_t)bz * SEQ_L + qg) * D_MODEL + h * HDIM;
#pragma unroll
        for (int nt = 0; nt < 4; nt++) {
            ushort4v pk;
#pragma unroll
            for (int r = 0; r < 4; r++) pk[r] = f2bf(o[g][nt][r]);
            *(ushort4v*)(obase + nt * 16 + quad * 4) = pk;
        }
    }
}

// ---------------------------------------------------------------------------
// Kernel 2b: merge split-K partials: A = (O0 + O1) / (l0 + l1), bf16.
// ---------------------------------------------------------------------------
__global__ __launch_bounds__(256) void merge_attn(
    const ushort* __restrict__ O0, const ushort* __restrict__ O1,
    const float* __restrict__ Lw, ushort* __restrict__ Aout)
{
    const int gid = blockIdx.x * 256 + threadIdx.x;
    const int i = gid * 8;
    const int row = i >> 10;            // bz*2048 + q
    const int h   = (i >> 6) & 15;
    const int bz  = row >> 11, q = row & 2047;
    const int li  = (bz * NHEADS + h) * SEQ_L + q;
    const float linv = 1.f / (Lw[li] + Lw[2 * NHEADS * SEQ_L + li]);

    uint4 a = *(const uint4*)(O0 + i);
    uint4 b = *(const uint4*)(O1 + i);
    unsigned aw[4] = {a.x, a.y, a.z, a.w};
    unsigned bw[4] = {b.x, b.y, b.z, b.w};
    uint4 res;
    unsigned rw[4];
#pragma unroll
    for (int k = 0; k < 4; k++) {
        float alo = __uint_as_float(aw[k] << 16);
        float ahi = __uint_as_float(aw[k] & 0xFFFF0000u);
        float blo = __uint_as_float(bw[k] << 16);
        float bhi = __uint_as_float(bw[k] & 0xFFFF0000u);
        float lo = (alo + blo) * linv;
        float hi = (ahi + bhi) * linv;
        rw[k] = (unsigned)f2bf(lo) | ((unsigned)f2bf(hi) << 16);
    }
    res.x = rw[0]; res.y = rw[1]; res.z = rw[2]; res.w = rw[3];
    *(uint4*)(Aout + i) = res;
}

// ---------------------------------------------------------------------------
// Kernel 3: output projection. 64x64xBK64 tiles, grid 16x64 = 1024 blocks,
// LDS 16 KB, SWAPPED operands -> C^T -> float4 stores.
// ---------------------------------------------------------------------------
__global__ __launch_bounds__(256, 4) void gemm_out(
    const ushort* __restrict__ A, const ushort* __restrict__ B,
    const float* __restrict__ bo, float* __restrict__ out)
{
    __shared__ ushort As[64 * 64];   // 8 KB
    __shared__ ushort Bs[64 * 64];   // 8 KB

    const int tid  = threadIdx.x;
    const int w    = tid >> 6;
    const int lane = tid & 63;
    const int l15  = lane & 15;
    const int quad = lane >> 4;

    const int bm = blockIdx.y * 64;
    const int bn = blockIdx.x * 64;

    const int ci0 = tid, ci1 = tid + 256;     // 512 chunks per tile
    const int r0 = ci0 >> 3, r1 = ci1 >> 3;
    const int s0 = ci0 & 7,  s1 = ci1 & 7;
    const ushort* aP0 = A + (size_t)(bm + r0) * 1024 + (s0 ^ (r0 & 7)) * 8;
    const ushort* aP1 = A + (size_t)(bm + r1) * 1024 + (s1 ^ (r1 & 7)) * 8;
    const ushort* bP0 = B + (size_t)(bn + r0) * 1024 + (s0 ^ (r0 & 7)) * 8;
    const ushort* bP1 = B + (size_t)(bn + r1) * 1024 + (s1 ^ (r1 & 7)) * 8;
    ushort* lA0 = &As[r0 * 64 + s0 * 8];
    ushort* lA1 = &As[r1 * 64 + s1 * 8];
    ushort* lB0 = &Bs[r0 * 64 + s0 * 8];
    ushort* lB1 = &Bs[r1 * 64 + s1 * 8];

    const int x7 = l15 & 7;

    floatx4 acc[4];
#pragma unroll
    for (int i = 0; i < 4; i++) acc[i] = (floatx4){0.f, 0.f, 0.f, 0.f};

    for (int k0 = 0; k0 < 1024; k0 += 64) {
        __syncthreads();
        gll16(aP0 + k0, lA0);
        gll16(aP1 + k0, lA1);
        gll16(bP0 + k0, lB0);
        gll16(bP1 + k0, lB1);
        __syncthreads();

#pragma unroll
        for (int kk = 0; kk < 2; kk++) {
            const int slot = ((kk * 4 + quad) ^ x7) * 8;
            short8 bf = *(const short8*)&Bs[(w * 16 + l15) * 64 + slot];
#pragma unroll
            for (int mi = 0; mi < 4; mi++) {
                short8 af = *(const short8*)&As[(mi * 16 + l15) * 64 + slot];
                acc[mi] = mfma16(bf, af, acc[mi]);
            }
        }
    }

    // D^T: lane holds x-row = l15, out-col = w*16 + quad*4 + r (consecutive)
    const int col0 = bn + w * 16 + quad * 4;
    const float4 bb4 = *(const float4*)&bo[col0];
#pragma unroll
    for (int mi = 0; mi < 4; mi++) {
        const int row = bm + mi * 16 + l15;
        float4 st;
        st.x = acc[mi][0] + bb4.x;
        st.y = acc[mi][1] + bb4.y;
        st.z = acc[mi][2] + bb4.z;
        st.w = acc[mi][3] + bb4.w;
        *(float4*)(out + (size_t)row * 1024 + col0) = st;
    }
}

// ---------------------------------------------------------------------------
extern "C" void kernel_launch(void* const* d_in, const int* in_sizes, int n_in,
                              void* d_out, int out_size, void* d_ws, size_t ws_size,
                              hipStream_t stream)
{
    const float* x   = (const float*)d_in[0];
    const float* Wq  = (const float*)d_in[1];
    const float* bq  = (const float*)d_in[2];
    const float* Wk  = (const float*)d_in[3];
    const float* bk  = (const float*)d_in[4];
    const float* Wv  = (const float*)d_in[5];
    const float* bv  = (const float*)d_in[6];
    const float* Wo  = (const float*)d_in[7];
    const float* bo  = (const float*)d_in[8];
    const float* lam = (const float*)d_in[9];
    float* out = (float*)d_out;

    const size_t NELEM = (size_t)NROWS * D_MODEL;   // 4194304
    ushort* Qw  = (ushort*)d_ws;                    //  8 MB
    ushort* Kw  = Qw + NELEM;                       //  8 MB
    ushort* Vw  = Kw + NELEM;                       //  8 MB
    ushort* O0  = Vw + NELEM;                       //  8 MB
    ushort* O1  = O0 + NELEM;                       //  8 MB
    ushort* XA  = O1 + NELEM;                       //  8 MB: xb, then merged A
    ushort* Wb3 = XA + NELEM;                       //  6 MB
    ushort* Wob = Wb3 + 3 * 1024 * 1024;            //  2 MB
    float*  Lw  = (float*)(Wob + 1024 * 1024);      //  512 KB

    dim3 gc(2048, 5);
    convert_bf16<<<gc, 256, 0, stream>>>(x, Wq, Wk, Wv, Wo, XA, Wb3, Wob);

    dim3 g1(3072 / 128, NROWS / 64);   // 24 x 64 = 1536 blocks
    gemm_qkv<<<g1, 256, 0, stream>>>(XA, Wb3, bq, bk, bv, Qw, Kw, Vw);

    dim3 g2(SEQ_L / 128, NHEADS, 4);   // z = batch*2 + key-split
    attn<<<g2, 256, 0, stream>>>(Qw, Kw, Vw, lam, O0, O1, Lw);

    merge_attn<<<NELEM / (256 * 8), 256, 0, stream>>>(O0, O1, Lw, XA);

    dim3 g3(1024 / 64, NROWS / 64);    // 16 x 64 = 1024 blocks
    gemm_out<<<g3, 256, 0, stream>>>(XA, Wob, bo, out);
}